// Round 8
// baseline (434.630 us; speedup 1.0000x reference)
//
#include <hip/hip_runtime.h>
#include <math.h>

#define N_SRC   200000
#define N_DST   50000
#define N_EDGES 800000
#define N_IN    256
#define N_OUT   128
#define CAP     48        // padded-CSR slots/row; P(deg>48 | Poisson(16)) ~ 1e-13/row

// ---- workspace layout (bytes), all 16B-aligned ----
#define WS_CNT   0            // int[50000*16], only [r*16] used (3.2 MB, 1 ctr / 64B line)
#define WS_WTW   3200000      // ushort[128*256] bf16 (W_w^T)
#define WS_WTB   3265536      // ushort[128*256] bf16 (W_b^T)
#define WS_SELF  3331072      // ushort[50000*128] bf16, PERMUTED cols (12.8 MB)
#define WS_Y     16131072     // ushort[200000*128] bf16, PERMUTED cols (51.2 MB)
#define WS_CSR   67331072     // int2[50000*48] (19.2 MB) -> total 86.5 MB

typedef short  bf16x8 __attribute__((ext_vector_type(8)));
typedef unsigned short u16x8 __attribute__((ext_vector_type(8)));
typedef float  f32x4  __attribute__((ext_vector_type(4)));

typedef const __attribute__((address_space(1))) void gv_t;
typedef __attribute__((address_space(3))) void lv_t;

__device__ inline unsigned short f2bf(float f) {
    unsigned u = __builtin_bit_cast(unsigned, f);
    u += 0x7fffu + ((u >> 16) & 1u);           // RNE
    return (unsigned short)(u >> 16);
}
__device__ inline float bf2f(unsigned short h) {
    return __builtin_bit_cast(float, (unsigned)h << 16);
}

// ---------------- init: weight transpose+bf16, zero padded counters ----------
__global__ __launch_bounds__(256) void k_init(const float* __restrict__ Ww,
                                              const float* __restrict__ Wb,
                                              unsigned short* __restrict__ Wtw,
                                              unsigned short* __restrict__ Wtb,
                                              int* __restrict__ cnt) {
    int tot = blockIdx.x * 256 + threadIdx.x;
    int sel = tot >> 15;
    int idx = tot & 32767;
    int n = idx >> 8, k = idx & 255;
    const float* src = sel ? Wb : Ww;
    unsigned short* dst = sel ? Wtb : Wtw;
    dst[n * 256 + k] = f2bf(src[k * 128 + n]);
    if (tot < N_DST) cnt[tot * 16] = 0;        // one counter per 64 B line
}

// ---------------- scatter: padded CSR build (separate; fusing it regressed) --
__global__ __launch_bounds__(256) void k_scatter(const int* __restrict__ erows,
                                                 const int* __restrict__ ecols,
                                                 const float* __restrict__ evals,
                                                 int* __restrict__ cnt,
                                                 int2* __restrict__ csr_pad) {
    int i = blockIdx.x * 256 + threadIdx.x;
    int r = erows[i];
    int rank = atomicAdd(&cnt[r * 16], 1);
    if (rank < CAP) {
        int2 cv;
        cv.x = ecols[i];
        cv.y = __builtin_bit_cast(int, evals[i]);
        csr_pad[(long)r * CAP + rank] = cv;
    }
}

// ---------------- gemm: m97-style 2-phase global_load_lds pipeline ----------
// blocks [0,3125): y' = x @ W_w ; blocks [3125,3907): self' = x[sn] @ W_b
// Per 64-row tile: A kt-slice (64x128B raw f32, 8KB) and B kt-slice
// (128x64B bf16, 8KB) double-buffered, staged by global_load_lds width-16
// (DMA, no VGPR round-trip -> compiler cannot sink the loads). One barrier
// per kt: stage(kt+1) issues BEFORE kt's compute, drains after it.
// Swizzle rule #21: LDS dest linear, global src inverse-permuted, ds_read
// permuted.  A slot = chunk^(row&7); B slot = quad^((row>>1)&3) (both 2-way).
// Output stored col-PERMUTED (c' = (j&15)*8 + (j>>4)): 16 B/thread reg stores.
#define GBIG  3125
#define GSELF 782

__global__ __launch_bounds__(256, 4) void k_gemm(
        const float* __restrict__ x, const int* __restrict__ sn,
        const unsigned short* __restrict__ Wtw, const unsigned short* __restrict__ Wtb,
        unsigned short* __restrict__ ybuf, unsigned short* __restrict__ selfp) {
    // 32 KB: A dbuf 2x8KB | B dbuf 2x8KB   (ushort indices)
    __shared__ __align__(16) unsigned short sm[16384];
    unsigned short* Ab[2] = { sm,        sm + 4096 };
    unsigned short* Bb[2] = { sm + 8192, sm + 12288 };

    const int tid = threadIdx.x;
    const int bid = blockIdx.x;
    const bool isBig = bid < GBIG;
    const unsigned short* Bt = isBig ? Wtw : Wtb;
    unsigned short* Y = isBig ? ybuf : selfp;
    const int M    = isBig ? N_SRC : N_DST;
    const int tile = isBig ? bid : bid - GBIG;

    const int lane = tid & 63, wid = tid >> 6;
    const int l15 = lane & 15, quad = lane >> 4;

    // ---- per-thread fixed staging sources (byte offsets) ----
    // A: instr q in {0,1}: row rl = (wid*2+q)*8 + (lane>>3); slot = lane&7 holds
    //    global chunk (lane&7)^((lane>>3)&7); kt adds kt*128 B.
    const char* xb = (const char*)x;
    long abase[2];
    #pragma unroll
    for (int q = 0; q < 2; q++) {
        int rl = (wid * 2 + q) * 8 + (lane >> 3);
        int row = tile * 64 + rl;
        if (row >= M) row = M - 1;
        if (!isBig) row = sn[row];
        abase[q] = (long)row * 1024 + (long)(((lane & 7) ^ ((lane >> 3) & 7)) << 4);
    }
    // B: instr q in {0,1}: row = (wid*2+q)*16 + (lane>>2); slot = lane&3 holds
    //    global chunk (lane&3)^((lane>>3)&3); kt adds kt*64 B.
    const char* btb = (const char*)Bt;
    long bbase[2];
    #pragma unroll
    for (int q = 0; q < 2; q++) {
        int row = (wid * 2 + q) * 16 + (lane >> 2);
        bbase[q] = (long)row * 512 + (long)(((lane & 3) ^ ((lane >> 3) & 3)) << 4);
    }

    f32x4 acc[8];
    #pragma unroll
    for (int t = 0; t < 8; t++) acc[t] = (f32x4){0.f, 0.f, 0.f, 0.f};

    // ---- prologue: stage kt=0 into buffer 0 ----
    #pragma unroll
    for (int q = 0; q < 2; q++) {
        __builtin_amdgcn_global_load_lds((gv_t*)(xb + abase[q]),
            (lv_t*)(Ab[0] + (wid * 2 + q) * 512), 16, 0, 0);
        __builtin_amdgcn_global_load_lds((gv_t*)(btb + bbase[q]),
            (lv_t*)(Bb[0] + (wid * 2 + q) * 512), 16, 0, 0);
    }
    __syncthreads();

    // ---- 2-phase K loop ----
    const int arow = (wid * 16 + l15) * 64;        // A row base (ush), 128 B rows
    const int aswz = l15 & 7;
    const int bswz = quad ^ ((l15 >> 1) & 3);
    int cur = 0;
    #pragma unroll
    for (int kt = 0; kt < 8; kt++) {
        if (kt < 7) {                               // stage kt+1 into other buffer
            #pragma unroll
            for (int q = 0; q < 2; q++) {
                __builtin_amdgcn_global_load_lds((gv_t*)(xb + abase[q] + (kt + 1) * 128),
                    (lv_t*)(Ab[cur ^ 1] + (wid * 2 + q) * 512), 16, 0, 0);
                __builtin_amdgcn_global_load_lds((gv_t*)(btb + bbase[q] + (kt + 1) * 64),
                    (lv_t*)(Bb[cur ^ 1] + (wid * 2 + q) * 512), 16, 0, 0);
            }
        }
        // compute on current buffers
        const unsigned short* A = Ab[cur];
        const unsigned short* B = Bb[cur];
        float4 a0 = *(const float4*)&A[arow + (((quad * 2)     ^ aswz) << 3)];
        float4 a1 = *(const float4*)&A[arow + (((quad * 2 + 1) ^ aswz) << 3)];
        bf16x8 af;
        af[0] = (short)f2bf(a0.x); af[1] = (short)f2bf(a0.y);
        af[2] = (short)f2bf(a0.z); af[3] = (short)f2bf(a0.w);
        af[4] = (short)f2bf(a1.x); af[5] = (short)f2bf(a1.y);
        af[6] = (short)f2bf(a1.z); af[7] = (short)f2bf(a1.w);
        #pragma unroll
        for (int t = 0; t < 8; t++) {
            bf16x8 bv = *(const bf16x8*)&B[(t * 16 + l15) * 32 + (bswz << 3)];
            acc[t] = __builtin_amdgcn_mfma_f32_16x16x32_bf16(af, bv, acc[t], 0, 0, 0);
        }
        __syncthreads();        // drains vmcnt (kt+1 loads overlapped kt compute)
        cur ^= 1;
    }

    // ---- epilogue: direct permuted-column register stores (no LDS) ----
    #pragma unroll
    for (int rg = 0; rg < 4; rg++) {
        int row = tile * 64 + wid * 16 + quad * 4 + rg;
        if (row < M) {
            u16x8 w;
            #pragma unroll
            for (int t = 0; t < 8; t++) w[t] = f2bf(acc[t][rg]);
            *(u16x8*)(Y + (long)row * 128 + l15 * 8) = w;
        }
    }
}

// ---------------- fused SpMM + bias + ELU + layernorm + affine ----------------
// 4 waves/block, one dst row per wave. y'/selfp' are col-PERMUTED:
// stored c' holds logical col j = ((c'&7)<<4) | (c'>>3). Lane handles
// c'=2*lane, 2*lane+1 -> contiguous dword loads; bias/scale/offs/out use j.
// Gather loop 16-deep (avg deg 16 -> usually ONE batch, 4 KB in flight/wave).
#define GATHER(j) \
    int   c##j = __shfl(cv.x, e0 + j, 64); \
    float v##j = __builtin_bit_cast(float, __shfl(cv.y, e0 + j, 64)); \
    unsigned p##j = *(const unsigned*)(y + (long)c##j * 128 + (lane << 1));
#define ACCUM(j) \
    a0 = fmaf(v##j, __builtin_bit_cast(float, p##j << 16), a0); \
    a1 = fmaf(v##j, __builtin_bit_cast(float, p##j & 0xffff0000u), a1);

__global__ __launch_bounds__(256) void k_sage(const unsigned short* __restrict__ y,
                                              const unsigned short* __restrict__ selfp,
                                              const int* __restrict__ cnt,
                                              const int2* __restrict__ csr_pad,
                                              const float* __restrict__ bw,
                                              const float* __restrict__ bb,
                                              const float* __restrict__ scale,
                                              const float* __restrict__ offs,
                                              float* __restrict__ out) {
    const int tid = threadIdx.x, lane = tid & 63, wid = tid >> 6;
    const int row = blockIdx.x * 4 + wid;
    const int m = min(cnt[row * 16], CAP);

    // inverse column permutation for this lane's two stored slots
    const int c0p = 2 * lane, c1p = 2 * lane + 1;
    const int j0 = ((c0p & 7) << 4) | (c0p >> 3);
    const int j1 = ((c1p & 7) << 4) | (c1p >> 3);

    // coalesced edge batch: one int2 per lane (zero-filled beyond m)
    int2 cv = (lane < m) ? csr_pad[(long)row * CAP + lane] : make_int2(0, 0);

    // self half (logical cols j0,j1)
    unsigned spk = *(const unsigned*)(selfp + (long)row * 128 + lane * 2);
    float s0 = bf2f((unsigned short)(spk & 0xffff)) + bb[j0];
    float s1 = bf2f((unsigned short)(spk >> 16))    + bb[j1];
    s0 = s0 > 0.f ? s0 : expm1f(s0);
    s1 = s1 > 0.f ? s1 : expm1f(s1);

    // neigh half: 16-deep pipelined gather
    float a0 = 0.f, a1 = 0.f;
    const int mm = (m + 15) & ~15;
    for (int e0 = 0; e0 < mm; e0 += 16) {
        GATHER(0)  GATHER(1)  GATHER(2)  GATHER(3)
        GATHER(4)  GATHER(5)  GATHER(6)  GATHER(7)
        GATHER(8)  GATHER(9)  GATHER(10) GATHER(11)
        GATHER(12) GATHER(13) GATHER(14) GATHER(15)
        ACCUM(0)  ACCUM(1)  ACCUM(2)  ACCUM(3)
        ACCUM(4)  ACCUM(5)  ACCUM(6)  ACCUM(7)
        ACCUM(8)  ACCUM(9)  ACCUM(10) ACCUM(11)
        ACCUM(12) ACCUM(13) ACCUM(14) ACCUM(15)
    }
    a0 += bw[j0];
    a1 += bw[j1];
    a0 = a0 > 0.f ? a0 : expm1f(a0);
    a1 = a1 > 0.f ? a1 : expm1f(a1);

    // layernorm over 256 values (4 per lane); order-independent
    float s  = s0 + s1 + a0 + a1;
    float s2 = s0 * s0 + s1 * s1 + a0 * a0 + a1 * a1;
    #pragma unroll
    for (int o = 32; o > 0; o >>= 1) {
        s  += __shfl_xor(s,  o, 64);
        s2 += __shfl_xor(s2, o, 64);
    }
    float mean = s * (1.f / 256.f);
    float var  = s2 * (1.f / 256.f) - mean * mean;
    float rstd = rsqrtf(var + 1e-9f);

    float* orow = out + (long)row * 256;
    orow[j0]       = (s0 - mean) * rstd * scale[j0]       + offs[j0];
    orow[j1]       = (s1 - mean) * rstd * scale[j1]       + offs[j1];
    orow[128 + j0] = (a0 - mean) * rstd * scale[128 + j0] + offs[128 + j0];
    orow[128 + j1] = (a1 - mean) * rstd * scale[128 + j1] + offs[128 + j1];
}

extern "C" void kernel_launch(void* const* d_in, const int* in_sizes, int n_in,
                              void* d_out, int out_size, void* d_ws, size_t ws_size,
                              hipStream_t stream) {
    const float* x     = (const float*)d_in[0];
    const int*   erows = (const int*)  d_in[1];
    const int*   ecols = (const int*)  d_in[2];
    const float* evals = (const float*)d_in[3];
    const int*   sn    = (const int*)  d_in[4];
    const float* Ww    = (const float*)d_in[5];
    const float* bw    = (const float*)d_in[6];
    const float* Wb    = (const float*)d_in[7];
    const float* bb    = (const float*)d_in[8];
    const float* scale = (const float*)d_in[9];
    const float* offs  = (const float*)d_in[10];
    float* out = (float*)d_out;

    char* ws = (char*)d_ws;
    int*   cnt     = (int*)  (ws + WS_CNT);
    unsigned short* Wtw   = (unsigned short*)(ws + WS_WTW);
    unsigned short* Wtb   = (unsigned short*)(ws + WS_WTB);
    unsigned short* selfp = (unsigned short*)(ws + WS_SELF);
    unsigned short* ybuf  = (unsigned short*)(ws + WS_Y);
    int2*  csr_pad = (int2*) (ws + WS_CSR);

    k_init    <<<256, 256, 0, stream>>>(Ww, Wb, Wtw, Wtb, cnt);
    k_scatter <<<N_EDGES / 256, 256, 0, stream>>>(erows, ecols, evals, cnt, csr_pad);
    k_gemm    <<<GBIG + GSELF, 256, 0, stream>>>(x, sn, Wtw, Wtb, ybuf, selfp);
    k_sage    <<<N_DST / 4, 256, 0, stream>>>(ybuf, selfp, cnt, csr_pad,
                                              bw, bb, scale, offs, out);
}

// Round 9
// 415.953 us; speedup vs baseline: 1.0449x; 1.0449x over previous
//
#include <hip/hip_runtime.h>
#include <math.h>

#define N_SRC   200000
#define N_DST   50000
#define N_EDGES 800000
#define N_IN    256
#define N_OUT   128
#define CAP     48        // padded-CSR slots/row; P(deg>48 | Poisson(16)) ~ 1e-13/row

// ---- workspace layout (bytes), all 16B-aligned ----
#define WS_CNT   0            // int[50000*16], only [r*16] used (3.2 MB, 1 ctr / 64B line)
#define WS_WTW   3200000      // ushort[128*256] bf16 (W_w^T)
#define WS_WTB   3265536      // ushort[128*256] bf16 (W_b^T)
#define WS_SELF  3331072      // ushort[50000*128] bf16, PERMUTED cols (12.8 MB)
#define WS_Y     16131072     // ushort[200000*128] bf16, PERMUTED cols (51.2 MB)
#define WS_CSR   67331072     // int2[50000*48] (19.2 MB) -> total 86.5 MB

typedef short  bf16x8 __attribute__((ext_vector_type(8)));
typedef unsigned short u16x8 __attribute__((ext_vector_type(8)));
typedef float  f32x4  __attribute__((ext_vector_type(4)));

typedef const __attribute__((address_space(1))) void gv_t;
typedef __attribute__((address_space(3))) void lv_t;

__device__ inline unsigned short f2bf(float f) {
    unsigned u = __builtin_bit_cast(unsigned, f);
    u += 0x7fffu + ((u >> 16) & 1u);           // RNE
    return (unsigned short)(u >> 16);
}
__device__ inline float bf2f(unsigned short h) {
    return __builtin_bit_cast(float, (unsigned)h << 16);
}

// ---------------- init: weight transpose+bf16, zero padded counters ----------
// Separate dispatch: gemm blocks consume Wt; no safe inter-block ordering in one kernel.
__global__ __launch_bounds__(256) void k_init(const float* __restrict__ Ww,
                                              const float* __restrict__ Wb,
                                              unsigned short* __restrict__ Wtw,
                                              unsigned short* __restrict__ Wtb,
                                              int* __restrict__ cnt) {
    int tot = blockIdx.x * 256 + threadIdx.x;
    int sel = tot >> 15;
    int idx = tot & 32767;
    int n = idx >> 8, k = idx & 255;
    const float* src = sel ? Wb : Ww;
    unsigned short* dst = sel ? Wtb : Wtw;
    dst[n * 256 + k] = f2bf(src[k * 128 + n]);
    if (tot < N_DST) cnt[tot * 16] = 0;        // one counter per 64 B line
}

// ---------------- fused: scatter (block range) + both MFMA GEMMs -------------
// blocks [0,782): scatter 1024 edges each (dispatched first; drains fast and
//                 interleaves into the gemm blocks' latency bubbles)
// blocks [782, 782+3125): y' = x @ W_w
// blocks [782+3125, 782+3907): self' = x[sn] @ W_b
//
// GEMM = R8 structure: per 64-row tile, A kt-slice (64x128B f32, 8KB) and
// B kt-slice (128x64B bf16, 8KB) double-buffered via global_load_lds width-16
// (DMA -> compiler cannot sink the loads). One barrier per kt; stage(kt+1)
// issues BEFORE kt's compute. Swizzle rule #21: linear LDS dest, inverse-
// permuted global src, permuted ds_read. A slot = chunk^(row&7);
// B slot = quad^((row>>1)&3). Output col-PERMUTED (c' = (j&15)*8 + (j>>4)).
#define GSCAT 782
#define GBIG  3125
#define GSELF 782

__global__ __launch_bounds__(256, 4) void k_fused(
        const float* __restrict__ x,
        const int* __restrict__ erows, const int* __restrict__ ecols,
        const float* __restrict__ evals, const int* __restrict__ sn,
        const unsigned short* __restrict__ Wtw, const unsigned short* __restrict__ Wtb,
        int* __restrict__ cnt, int2* __restrict__ csr_pad,
        unsigned short* __restrict__ ybuf, unsigned short* __restrict__ selfp) {
    // 32 KB: A dbuf 2x8KB | B dbuf 2x8KB   (ushort indices)
    __shared__ __align__(16) unsigned short sm[16384];
    unsigned short* Ab[2] = { sm,        sm + 4096 };
    unsigned short* Bb[2] = { sm + 8192, sm + 12288 };

    const int tid = threadIdx.x;
    const int bid = blockIdx.x;

    if (bid < GSCAT) {                       // ---- scatter range ----
        const int base = bid * 1024 + tid;   // 782*1024 = 800768 >= 800000
        #pragma unroll
        for (int i = 0; i < 4; i++) {
            int e = base + i * 256;
            if (e < N_EDGES) {
                int r = erows[e];
                int rank = atomicAdd(&cnt[r * 16], 1);
                if (rank < CAP) {
                    int2 cv;
                    cv.x = ecols[e];
                    cv.y = __builtin_bit_cast(int, evals[e]);
                    csr_pad[(long)r * CAP + rank] = cv;
                }
            }
        }
        return;
    }

    const int gb = bid - GSCAT;
    const bool isBig = gb < GBIG;
    const unsigned short* Bt = isBig ? Wtw : Wtb;
    unsigned short* Y = isBig ? ybuf : selfp;
    const int M    = isBig ? N_SRC : N_DST;
    const int tile = isBig ? gb : gb - GBIG;

    const int lane = tid & 63, wid = tid >> 6;
    const int l15 = lane & 15, quad = lane >> 4;

    // ---- per-thread fixed staging sources (byte offsets) ----
    const char* xb = (const char*)x;
    long abase[2];
    #pragma unroll
    for (int q = 0; q < 2; q++) {
        int rl = (wid * 2 + q) * 8 + (lane >> 3);
        int row = tile * 64 + rl;
        if (row >= M) row = M - 1;
        if (!isBig) row = sn[row];
        abase[q] = (long)row * 1024 + (long)(((lane & 7) ^ ((lane >> 3) & 7)) << 4);
    }
    const char* btb = (const char*)Bt;
    long bbase[2];
    #pragma unroll
    for (int q = 0; q < 2; q++) {
        int row = (wid * 2 + q) * 16 + (lane >> 2);
        bbase[q] = (long)row * 512 + (long)(((lane & 3) ^ ((lane >> 3) & 3)) << 4);
    }

    f32x4 acc[8];
    #pragma unroll
    for (int t = 0; t < 8; t++) acc[t] = (f32x4){0.f, 0.f, 0.f, 0.f};

    // ---- prologue: stage kt=0 into buffer 0 ----
    #pragma unroll
    for (int q = 0; q < 2; q++) {
        __builtin_amdgcn_global_load_lds((gv_t*)(xb + abase[q]),
            (lv_t*)(Ab[0] + (wid * 2 + q) * 512), 16, 0, 0);
        __builtin_amdgcn_global_load_lds((gv_t*)(btb + bbase[q]),
            (lv_t*)(Bb[0] + (wid * 2 + q) * 512), 16, 0, 0);
    }
    __syncthreads();

    // ---- 2-phase K loop ----
    const int arow = (wid * 16 + l15) * 64;        // A row base (ush), 128 B rows
    const int aswz = l15 & 7;
    const int bswz = quad ^ ((l15 >> 1) & 3);
    int cur = 0;
    #pragma unroll
    for (int kt = 0; kt < 8; kt++) {
        if (kt < 7) {                               // stage kt+1 into other buffer
            #pragma unroll
            for (int q = 0; q < 2; q++) {
                __builtin_amdgcn_global_load_lds((gv_t*)(xb + abase[q] + (kt + 1) * 128),
                    (lv_t*)(Ab[cur ^ 1] + (wid * 2 + q) * 512), 16, 0, 0);
                __builtin_amdgcn_global_load_lds((gv_t*)(btb + bbase[q] + (kt + 1) * 64),
                    (lv_t*)(Bb[cur ^ 1] + (wid * 2 + q) * 512), 16, 0, 0);
            }
        }
        const unsigned short* A = Ab[cur];
        const unsigned short* B = Bb[cur];
        float4 a0 = *(const float4*)&A[arow + (((quad * 2)     ^ aswz) << 3)];
        float4 a1 = *(const float4*)&A[arow + (((quad * 2 + 1) ^ aswz) << 3)];
        bf16x8 af;
        af[0] = (short)f2bf(a0.x); af[1] = (short)f2bf(a0.y);
        af[2] = (short)f2bf(a0.z); af[3] = (short)f2bf(a0.w);
        af[4] = (short)f2bf(a1.x); af[5] = (short)f2bf(a1.y);
        af[6] = (short)f2bf(a1.z); af[7] = (short)f2bf(a1.w);
        #pragma unroll
        for (int t = 0; t < 8; t++) {
            bf16x8 bv = *(const bf16x8*)&B[(t * 16 + l15) * 32 + (bswz << 3)];
            acc[t] = __builtin_amdgcn_mfma_f32_16x16x32_bf16(af, bv, acc[t], 0, 0, 0);
        }
        __syncthreads();        // drains vmcnt (kt+1 loads overlapped kt compute)
        cur ^= 1;
    }

    // ---- epilogue: direct permuted-column register stores (no LDS) ----
    #pragma unroll
    for (int rg = 0; rg < 4; rg++) {
        int row = tile * 64 + wid * 16 + quad * 4 + rg;
        if (row < M) {
            u16x8 w;
            #pragma unroll
            for (int t = 0; t < 8; t++) w[t] = f2bf(acc[t][rg]);
            *(u16x8*)(Y + (long)row * 128 + l15 * 8) = w;
        }
    }
}

// ---------------- fused SpMM + bias + ELU + layernorm + affine ----------------
// 4 waves/block, one dst row per wave. y'/selfp' are col-PERMUTED:
// stored c' holds logical col j = ((c'&7)<<4) | (c'>>3). Lane handles
// c'=2*lane, 2*lane+1 -> contiguous dword loads; bias/scale/offs/out use j.
// Gather loop 16-deep (avg deg 16 -> usually ONE batch, 4 KB in flight/wave).
#define GATHER(j) \
    int   c##j = __shfl(cv.x, e0 + j, 64); \
    float v##j = __builtin_bit_cast(float, __shfl(cv.y, e0 + j, 64)); \
    unsigned p##j = *(const unsigned*)(y + (long)c##j * 128 + (lane << 1));
#define ACCUM(j) \
    a0 = fmaf(v##j, __builtin_bit_cast(float, p##j << 16), a0); \
    a1 = fmaf(v##j, __builtin_bit_cast(float, p##j & 0xffff0000u), a1);

__global__ __launch_bounds__(256) void k_sage(const unsigned short* __restrict__ y,
                                              const unsigned short* __restrict__ selfp,
                                              const int* __restrict__ cnt,
                                              const int2* __restrict__ csr_pad,
                                              const float* __restrict__ bw,
                                              const float* __restrict__ bb,
                                              const float* __restrict__ scale,
                                              const float* __restrict__ offs,
                                              float* __restrict__ out) {
    const int tid = threadIdx.x, lane = tid & 63, wid = tid >> 6;
    const int row = blockIdx.x * 4 + wid;
    const int m = min(cnt[row * 16], CAP);

    // inverse column permutation for this lane's two stored slots
    const int c0p = 2 * lane, c1p = 2 * lane + 1;
    const int j0 = ((c0p & 7) << 4) | (c0p >> 3);
    const int j1 = ((c1p & 7) << 4) | (c1p >> 3);

    // coalesced edge batch: one int2 per lane (zero-filled beyond m)
    int2 cv = (lane < m) ? csr_pad[(long)row * CAP + lane] : make_int2(0, 0);

    // self half (logical cols j0,j1)
    unsigned spk = *(const unsigned*)(selfp + (long)row * 128 + lane * 2);
    float s0 = bf2f((unsigned short)(spk & 0xffff)) + bb[j0];
    float s1 = bf2f((unsigned short)(spk >> 16))    + bb[j1];
    s0 = s0 > 0.f ? s0 : expm1f(s0);
    s1 = s1 > 0.f ? s1 : expm1f(s1);

    // neigh half: 16-deep pipelined gather
    float a0 = 0.f, a1 = 0.f;
    const int mm = (m + 15) & ~15;
    for (int e0 = 0; e0 < mm; e0 += 16) {
        GATHER(0)  GATHER(1)  GATHER(2)  GATHER(3)
        GATHER(4)  GATHER(5)  GATHER(6)  GATHER(7)
        GATHER(8)  GATHER(9)  GATHER(10) GATHER(11)
        GATHER(12) GATHER(13) GATHER(14) GATHER(15)
        ACCUM(0)  ACCUM(1)  ACCUM(2)  ACCUM(3)
        ACCUM(4)  ACCUM(5)  ACCUM(6)  ACCUM(7)
        ACCUM(8)  ACCUM(9)  ACCUM(10) ACCUM(11)
        ACCUM(12) ACCUM(13) ACCUM(14) ACCUM(15)
    }
    a0 += bw[j0];
    a1 += bw[j1];
    a0 = a0 > 0.f ? a0 : expm1f(a0);
    a1 = a1 > 0.f ? a1 : expm1f(a1);

    // layernorm over 256 values (4 per lane); order-independent
    float s  = s0 + s1 + a0 + a1;
    float s2 = s0 * s0 + s1 * s1 + a0 * a0 + a1 * a1;
    #pragma unroll
    for (int o = 32; o > 0; o >>= 1) {
        s  += __shfl_xor(s,  o, 64);
        s2 += __shfl_xor(s2, o, 64);
    }
    float mean = s * (1.f / 256.f);
    float var  = s2 * (1.f / 256.f) - mean * mean;
    float rstd = rsqrtf(var + 1e-9f);

    float* orow = out + (long)row * 256;
    orow[j0]       = (s0 - mean) * rstd * scale[j0]       + offs[j0];
    orow[j1]       = (s1 - mean) * rstd * scale[j1]       + offs[j1];
    orow[128 + j0] = (a0 - mean) * rstd * scale[128 + j0] + offs[128 + j0];
    orow[128 + j1] = (a1 - mean) * rstd * scale[128 + j1] + offs[128 + j1];
}

extern "C" void kernel_launch(void* const* d_in, const int* in_sizes, int n_in,
                              void* d_out, int out_size, void* d_ws, size_t ws_size,
                              hipStream_t stream) {
    const float* x     = (const float*)d_in[0];
    const int*   erows = (const int*)  d_in[1];
    const int*   ecols = (const int*)  d_in[2];
    const float* evals = (const float*)d_in[3];
    const int*   sn    = (const int*)  d_in[4];
    const float* Ww    = (const float*)d_in[5];
    const float* bw    = (const float*)d_in[6];
    const float* Wb    = (const float*)d_in[7];
    const float* bb    = (const float*)d_in[8];
    const float* scale = (const float*)d_in[9];
    const float* offs  = (const float*)d_in[10];
    float* out = (float*)d_out;

    char* ws = (char*)d_ws;
    int*   cnt     = (int*)  (ws + WS_CNT);
    unsigned short* Wtw   = (unsigned short*)(ws + WS_WTW);
    unsigned short* Wtb   = (unsigned short*)(ws + WS_WTB);
    unsigned short* selfp = (unsigned short*)(ws + WS_SELF);
    unsigned short* ybuf  = (unsigned short*)(ws + WS_Y);
    int2*  csr_pad = (int2*) (ws + WS_CSR);

    k_init  <<<256, 256, 0, stream>>>(Ww, Wb, Wtw, Wtb, cnt);
    k_fused <<<GSCAT + GBIG + GSELF, 256, 0, stream>>>(x, erows, ecols, evals, sn,
                                                       Wtw, Wtb, cnt, csr_pad, ybuf, selfp);
    k_sage  <<<N_DST / 4, 256, 0, stream>>>(ybuf, selfp, cnt, csr_pad,
                                            bw, bb, scale, offs, out);
}